// Round 3
// baseline (341.683 us; speedup 1.0000x reference)
//
#include <hip/hip_runtime.h>

// Retrace loss: per-row backward affine recurrence y[s] = A[s]*y[s-1] + B[s],
// solved with a shuffle-based affine-map scan.
//
// R3 structure: one block per row, 1024 threads x 4 elements. Each thread
// issues exactly ONE float4 load per array (6 independent loads, one waitcnt,
// one memory-latency exposure per block) and lane addresses are 16B apart ->
// every load instruction covers fully-utilized contiguous cache lines.
// VGPR budget stays ~48 so the compiler keeps all loads in flight (the R2
// EPT=16 version needed 96+ VGPRs for its prefetch; the compiler serialized
// it into waitcnt-separated groups -> latency-bound at 1.6 TB/s).
// Shifted-window (u=t+1) values come from __shfl_up + a 16-float LDS handoff
// at wave boundaries. 3 barriers per block total.

#define NROWS 4096
#define TLEN  4096
#define BLOCK 1024
#define EPT   4
#define NWAVES (BLOCK / 64)

__global__ __launch_bounds__(BLOCK) void retrace_main(
    const float* __restrict__ Q,
    const float* __restrict__ eQ,
    const float* __restrict__ tQ,
    const float* __restrict__ rw,
    const float* __restrict__ tpp,
    const float* __restrict__ bpp,
    double* __restrict__ partials)
{
    constexpr float G = 0.99f;
    __shared__ float sT[NWAVES], sP[NWAVES], sQ[NWAVES], sE[NWAVES];
    __shared__ float sWA[NWAVES], sWB[NWAVES];
    __shared__ float sRed[NWAVES];

    const int tid  = threadIdx.x;
    const int lane = tid & 63;
    const int wv   = tid >> 6;
    const long long base = (long long)blockIdx.x * TLEN;
    // thread tid owns backward indices s in [4*tid, 4*tid+4);
    // element window [ua, ua+4), ua descends with tid -> contiguous coverage.
    const int ua = (TLEN - EPT) - EPT * tid;   // 4092 - 4*tid, 16B aligned

    // ---- One float4 load per array: 6 independent loads, single wait ----
    const float4 R4  = *(const float4*)(rw  + base + ua);
    const float4 T4  = *(const float4*)(tpp + base + ua);
    const float4 P4  = *(const float4*)(bpp + base + ua);
    const float4 Tq4 = *(const float4*)(tQ  + base + ua);
    const float4 E4  = *(const float4*)(eQ  + base + ua);
    const float4 Qm4 = *(const float4*)(Q   + base + ua);

    // ---- Wave-boundary handoff of element-0 values (needed as u = ua+4
    //      by the next-higher tid, which is lane 0 of the NEXT wave) ----
    if (lane == 63) { sT[wv] = T4.x; sP[wv] = P4.x; sQ[wv] = Tq4.x; sE[wv] = E4.x; }
    __syncthreads();

    float t4v = __shfl_up(T4.x,  1, 64);
    float p4v = __shfl_up(P4.x,  1, 64);
    float q4v = __shfl_up(Tq4.x, 1, 64);
    float e4v = __shfl_up(E4.x,  1, 64);
    if (lane == 0 && wv > 0) {
        t4v = sT[wv - 1]; p4v = sP[wv - 1]; q4v = sQ[wv - 1]; e4v = sE[wv - 1];
    }

    const float rv[4] = {R4.x,  R4.y,  R4.z,  R4.w};
    const float tv[4] = {T4.x,  T4.y,  T4.z,  T4.w};
    const float pv[4] = {P4.x,  P4.y,  P4.z,  P4.w};
    const float qv[4] = {Tq4.x, Tq4.y, Tq4.z, Tq4.w};
    const float ev[4] = {E4.x,  E4.y,  E4.z,  E4.w};
    const float qm[4] = {Qm4.x, Qm4.y, Qm4.z, Qm4.w};

    // ---- Build the 4 affine maps (idx = m-1, m in [1,4]) ----
    // Map m: A = G*c[u], B = 100*r[u-1] + G*(eq[u] - c[u]*tq[u]), u = ua+m.
    float Aa[EPT], Bb[EPT];
    #pragma unroll
    for (int m = 1; m <= EPT - 1; ++m) {
        const float c  = __expf(fminf(tv[m] - pv[m], 0.0f));
        const float gc = G * c;
        Aa[m - 1] = gc;
        Bb[m - 1] = fmaf(100.0f, rv[m - 1], fmaf(-gc, qv[m], G * ev[m]));
    }
    if (tid == 0) {
        // s = 0: y = tQ[T-1] exactly (A = 0 kills any prior state).
        Aa[EPT - 1] = 0.0f;
        Bb[EPT - 1] = qv[EPT - 1];     // tQ[base + TLEN - 1]
    } else {
        const float c  = __expf(fminf(t4v - p4v, 0.0f));
        const float gc = G * c;
        Aa[EPT - 1] = gc;
        Bb[EPT - 1] = fmaf(100.0f, rv[EPT - 1], fmaf(-gc, q4v, G * e4v));
    }

    // ---- Local sequential composite (maps applied idx = EPT-1 down to 0) ----
    float Ac = 1.0f, Bc = 0.0f;
    #pragma unroll
    for (int k = 0; k < EPT; ++k) {
        const int idx = EPT - 1 - k;
        Bc = fmaf(Aa[idx], Bc, Bb[idx]);
        Ac = Aa[idx] * Ac;
    }

    // ---- Wave-level inclusive scan of affine maps (no barriers) ----
    float Ai = Ac, Bi = Bc;
    #pragma unroll
    for (int off = 1; off < 64; off <<= 1) {
        const float Ap = __shfl_up(Ai, off, 64);
        const float Bp = __shfl_up(Bi, off, 64);
        if (lane >= off) {
            Bi = fmaf(Ai, Bp, Bi);
            Ai = Ai * Ap;
        }
    }

    // ---- Cross-wave combine: 16 wave composites through LDS ----
    if (lane == 63) { sWA[wv] = Ai; sWB[wv] = Bi; }
    __syncthreads();
    // Incoming state for this wave = composite of waves 0..wv-1 applied to 0.
    // (Wave 0 contains thread 0's s=0 map with A=0, so only B survives.)
    float Bp = 0.0f;
    #pragma unroll
    for (int j = 0; j < NWAVES - 1; ++j)
        if (j < wv) Bp = fmaf(sWA[j], Bp, sWB[j]);

    // Exclusive-within-wave prefix, then compose with incoming wave state.
    float Ae = __shfl_up(Ai, 1, 64);
    float Be = __shfl_up(Bi, 1, 64);
    if (lane == 0) { Ae = 1.0f; Be = 0.0f; }
    float y = fmaf(Ae, Bp, Be);            // y entering this thread's chunk

    // ---- Apply maps locally + accumulate squared error vs Q ----
    float acc = 0.0f;
    #pragma unroll
    for (int k = 0; k < EPT; ++k) {
        const int idx = EPT - 1 - k;
        y = fmaf(Aa[idx], y, Bb[idx]);     // y = Q_ret[t], t = ua + idx
        const float d = qm[idx] - y;
        acc = fmaf(d, d, acc);
    }

    // ---- Block reduction: wave shuffle (width 64) + tiny LDS combine ----
    #pragma unroll
    for (int off = 32; off > 0; off >>= 1)
        acc += __shfl_down(acc, off, 64);
    if (lane == 0) sRed[wv] = acc;
    __syncthreads();
    if (tid == 0) {
        float s = 0.0f;
        #pragma unroll
        for (int j = 0; j < NWAVES; ++j) s += sRed[j];
        partials[blockIdx.x] = (double)s;  // every block writes its slot -> poison-safe
    }
}

__global__ __launch_bounds__(256) void retrace_finalize(
    const double* __restrict__ partials, float* __restrict__ out)
{
    __shared__ double sRed[4];
    double s = 0.0;
    for (int i = threadIdx.x; i < NROWS; i += 256) s += partials[i];
    #pragma unroll
    for (int off = 32; off > 0; off >>= 1)
        s += __shfl_down(s, off, 64);
    if ((threadIdx.x & 63) == 0) sRed[threadIdx.x >> 6] = s;
    __syncthreads();
    if (threadIdx.x == 0) {
        const double tot = sRed[0] + sRed[1] + sRed[2] + sRed[3];
        out[0] = (float)(tot / ((double)NROWS * (double)TLEN));
    }
}

extern "C" void kernel_launch(void* const* d_in, const int* in_sizes, int n_in,
                              void* d_out, int out_size, void* d_ws, size_t ws_size,
                              hipStream_t stream)
{
    // setup_inputs order: Q, expected_target_Q, target_Q, rewards,
    //                     target_policy_probs, behaviour_policy_probs
    const float* Q   = (const float*)d_in[0];
    const float* eQ  = (const float*)d_in[1];
    const float* tQ  = (const float*)d_in[2];
    const float* rw  = (const float*)d_in[3];
    const float* tpp = (const float*)d_in[4];
    const float* bpp = (const float*)d_in[5];
    double* partials = (double*)d_ws;       // 4096 doubles = 32 KB scratch

    retrace_main<<<NROWS, BLOCK, 0, stream>>>(Q, eQ, tQ, rw, tpp, bpp, partials);
    retrace_finalize<<<1, 256, 0, stream>>>(partials, (float*)d_out);
}